// Round 3
// baseline (216.672 us; speedup 1.0000x reference)
//
#include <hip/hip_runtime.h>
#include <hip/hip_bf16.h>
#include <math.h>

#define NTOK 65536
#define DMODEL 256
#define NEXP 8
#define CAP 65536
#define MAXTILES 1040
#define CSTRIDE 64   // counter spacing in ints (256 B) - one L2 line per expert

typedef __bf16 bf16_t;
typedef __bf16 bf16x8 __attribute__((ext_vector_type(8)));
typedef float f32x4 __attribute__((ext_vector_type(4)));

// async global->LDS, 16B per lane. Global addr may be per-lane (gather);
// LDS dest = wave-uniform base + lane*16.
__device__ inline void async16(const void* g, void* l) {
  __builtin_amdgcn_global_load_lds(
      (const __attribute__((address_space(1))) unsigned int*)g,
      (__attribute__((address_space(3))) unsigned int*)l, 16, 0, 0);
}

// Prep: zero spread counters + transpose gate weights fp32 [E][D] -> [D][E].
__global__ void prep_kernel(const float* __restrict__ wg, float* __restrict__ wgT,
                            int* __restrict__ counts) {
  int t = blockIdx.x * 256 + threadIdx.x;
  if (t < NEXP * DMODEL) wgT[t] = wg[(t & 7) * 256 + (t >> 3)];
  if (t < NEXP * CSTRIDE) counts[t] = 0;
}

// Cast W1/W2 fp32 [e][k][n] -> bf16 transposed [e][n][k] via 32x32 LDS tile.
__global__ __launch_bounds__(256) void castT_kernel(
    const float* __restrict__ W1, const float* __restrict__ W2,
    bf16_t* __restrict__ w1t, bf16_t* __restrict__ w2t) {
  __shared__ float tile[32][33];
  const int m = blockIdx.z;
  const float* src = (m < 8) ? (W1 + (size_t)m * 65536) : (W2 + (size_t)(m - 8) * 65536);
  bf16_t* dst = (m < 8) ? (w1t + (size_t)m * 65536) : (w2t + (size_t)(m - 8) * 65536);
  const int x0 = blockIdx.x * 32, y0 = blockIdx.y * 32;
  const int tx = threadIdx.x, ty = threadIdx.y;
#pragma unroll
  for (int i = 0; i < 4; ++i)
    tile[ty + i * 8][tx] = src[(size_t)(y0 + ty + i * 8) * 256 + x0 + tx];
  __syncthreads();
#pragma unroll
  for (int i = 0; i < 4; ++i)
    dst[(size_t)(x0 + ty + i * 8) * 256 + y0 + tx] = (bf16_t)tile[tx][ty + i * 8];
}

// Gate v7 (unchanged from validated round-1 version; latency-bound at ~43us,
// to be attacked separately).
__global__ __launch_bounds__(256) void gate_kernel(
    const float* __restrict__ x, const float* __restrict__ wgT,
    bf16_t* __restrict__ xb, float* __restrict__ gateval,
    int* __restrict__ counts, int* __restrict__ idxbuf) {
  __shared__ __align__(16) float xs[64 * 256];   // 64 KB, xor-swizzled rows
  __shared__ double part[3][64][9];              // +1 pad: 18-word stride, 2-way (free)
  const int th = threadIdx.x;
  const int lane = th & 63;
  const int wv = th >> 6;                        // wave id = segment 0..3
  const int tokbase = blockIdx.x * 64;

  // Stage: 4096 16B slots; physical slot p = i*256+th holds logical
  // (r = p>>6, c = (p&63) ^ (r&31)). Source is per-lane, dest linear.
#pragma unroll
  for (int i = 0; i < 16; ++i) {
    int p = i * 256 + th;
    int r = p >> 6;
    int c = (p & 63) ^ (r & 31);
    async16(x + (size_t)(tokbase + r) * 256 + c * 4,
            &xs[(i * 256 + wv * 64) * 4]);
  }
  __syncthreads();  // drains vmcnt (compiler emits waitcnt before s_barrier)

  // Cast pass: issue the 32 MB of bf16 stores early so they drain
  // under the compute below. Output tile is contiguous: 2048 16B slots.
#pragma unroll
  for (int i = 0; i < 8; ++i) {
    int p = i * 256 + th;                 // bf16 16B slot: r = p>>5, cb = p&31
    int r = p >> 5, cb = p & 31;
    int mk = r & 31;
    f32x4 a = *(const f32x4*)&xs[r * 256 + (((2 * cb) ^ mk) * 4)];
    f32x4 b = *(const f32x4*)&xs[r * 256 + (((2 * cb + 1) ^ mk) * 4)];
    bf16x8 bv;
    bv[0] = (bf16_t)a[0]; bv[1] = (bf16_t)a[1];
    bv[2] = (bf16_t)a[2]; bv[3] = (bf16_t)a[3];
    bv[4] = (bf16_t)b[0]; bv[5] = (bf16_t)b[1];
    bv[6] = (bf16_t)b[2]; bv[7] = (bf16_t)b[3];
    *(bf16x8*)(xb + (size_t)tokbase * 256 + (size_t)p * 8) = bv;
  }

  // Partial dots: thread (tok=lane, seg=wv) covers dims [seg*64, seg*64+64).
  const float* wp = wgT + wv * 64 * 8;    // [64 dims][8 experts], wave-uniform
  const int xm = lane & 31;
  double acc[8] = {0, 0, 0, 0, 0, 0, 0, 0};
#pragma unroll
  for (int u = 0; u < 8; ++u) {           // 8-dim chain u (dims seg*64+u*8..+7)
    int c0 = 16 * wv + 2 * u;
    f32x4 a = *(const f32x4*)&xs[lane * 256 + ((c0 ^ xm) * 4)];
    f32x4 b = *(const f32x4*)&xs[lane * 256 + (((c0 + 1) ^ xm) * 4)];
    float xv[8] = {a[0], a[1], a[2], a[3], b[0], b[1], b[2], b[3]};
    float s[8] = {0.f, 0.f, 0.f, 0.f, 0.f, 0.f, 0.f, 0.f};
#pragma unroll
    for (int j = 0; j < 8; ++j) {         // vectorized weights: 2x16B per dim
      f32x4 w0 = *(const f32x4*)&wp[(u * 8 + j) * 8];
      f32x4 w1 = *(const f32x4*)&wp[(u * 8 + j) * 8 + 4];
      s[0] = fmaf(xv[j], w0[0], s[0]); s[1] = fmaf(xv[j], w0[1], s[1]);
      s[2] = fmaf(xv[j], w0[2], s[2]); s[3] = fmaf(xv[j], w0[3], s[3]);
      s[4] = fmaf(xv[j], w1[0], s[4]); s[5] = fmaf(xv[j], w1[1], s[5]);
      s[6] = fmaf(xv[j], w1[2], s[6]); s[7] = fmaf(xv[j], w1[3], s[7]);
    }
#pragma unroll
    for (int e = 0; e < 8; ++e) acc[e] += (double)s[e];
  }

  if (wv > 0) {
#pragma unroll
    for (int e = 0; e < 8; ++e) part[wv - 1][lane][e] = acc[e];
  }
  __syncthreads();
  if (wv == 0) {
#pragma unroll
    for (int s2 = 0; s2 < 3; ++s2)
#pragma unroll
      for (int e = 0; e < 8; ++e) acc[e] += part[s2][lane][e];
    double m = acc[0]; int bi = 0;
#pragma unroll
    for (int e = 1; e < 8; ++e) if (acc[e] > m) { m = acc[e]; bi = e; }
    float denom = 0.f;
#pragma unroll
    for (int e = 0; e < 8; ++e) denom += __expf((float)(acc[e] - m));
    const int tok = tokbase + lane;
    gateval[tok] = 1.0f / denom;
    unsigned long long mymask = 0;
#pragma unroll
    for (int e = 0; e < NEXP; ++e) {
      unsigned long long mk = __ballot(bi == e);
      if (lane == e) mymask = mk;
    }
    int mybase = 0;
    if (lane < NEXP) mybase = atomicAdd(&counts[lane * CSTRIDE], (int)__popcll(mymask));
#pragma unroll
    for (int e = 0; e < NEXP; ++e) {
      unsigned long long mk = __ballot(bi == e);
      int b = __shfl(mybase, e, 64);
      if (bi == e) {
        int pos = b + (int)__popcll(mk & ((1ull << lane) - 1ull));
        idxbuf[e * CAP + pos] = tok;
      }
    }
  }
}

// Scan: token bases + device-side tile list (e in bits 0..2, tm in bits 3+).
// Tiles are 64 rows.
__global__ void scan_kernel(const int* __restrict__ counts, int* __restrict__ bases,
                            int* __restrict__ tl, int* __restrict__ ntiles) {
  int t = threadIdx.x;
  if (t == 0) {
    int s = 0, n = 0;
    for (int e = 0; e < NEXP; ++e) {
      bases[e] = s; s += counts[e * CSTRIDE];
      n += (counts[e * CSTRIDE] + 63) >> 6;
    }
    *ntiles = n;
  }
  if (t < NEXP) {
    int off = 0;
    for (int j = 0; j < t; ++j) off += (counts[j * CSTRIDE] + 63) >> 6;
    int n = (counts[t * CSTRIDE] + 63) >> 6;
    for (int k = 0; k < n; ++k) tl[off + k] = t | (k << 3);
  }
}

// Fused MoE GEMM v2: h tile OVERLAYS the x tile in LDS (phase 1 finishes all
// xs reads before the h epilogue writes; one extra barrier guards the swap).
// LDS 66 KB -> 33 KB => 4 blocks/CU (16 waves/CU) instead of 2: round-2
// counters showed 16% occupancy with every pipe <20% (latency-bound serial
// chain per block); 4 independent blocks/CU co-schedule the stages
// (gather / phase1 / phase2 / store) across blocks.
//  - x tile staged once via global_load_lds, source pre-swizzled (16B slot
//    s' holds logical slot s'^(row&31)) -> fragment ds_read_b128 2-way (free).
//  - W1/W2 fragments read DIRECTLY from global (weights 2x2 MB bf16,
//    L2-resident): no B staging, no per-K-step barriers.
//  - __launch_bounds__(256,4) pins VGPR <= 128 so 16 waves/CU fit.
__global__ __launch_bounds__(256, 4) void moe_gemm_kernel(
    const bf16_t* __restrict__ xb, const bf16_t* __restrict__ w1t,
    const bf16_t* __restrict__ w2t, const float* __restrict__ b1,
    const float* __restrict__ b2, const float* __restrict__ gateval,
    const int* __restrict__ counts, const int* __restrict__ bases,
    const int* __restrict__ idxbuf, const int* __restrict__ tl,
    const int* __restrict__ ntiles, float* __restrict__ out) {
  if ((int)blockIdx.x >= *ntiles) return;
  const int tle = tl[blockIdx.x];
  const int e = tle & 7, tm = tle >> 3;
  const int cnt = counts[e * CSTRIDE];
  (void)bases;
  __shared__ __align__(16) bf16_t ts[64 * 256];   // 32 KB: x tile, then h tile
  __shared__ int sidx[64];
  __shared__ float sgv[64];
  const int th = threadIdx.x;
  const int lane = th & 63, wv = th >> 6;
  const int lr = lane & 15, lq = lane >> 4;
  if (th < 64) {
    int r = tm * 64 + th;
    int t = idxbuf[e * CAP + (r < cnt ? r : cnt - 1)];
    sidx[th] = t;
    sgv[th] = gateval[t];
  }
  __syncthreads();
  // Stage x tile: 2048 16B slots; physical slot p holds logical k-slot
  // (p&31)^(r&31) of row r = p>>5. Source per-lane, dest linear.
#pragma unroll
  for (int i = 0; i < 8; ++i) {
    int p = i * 256 + th;
    int r = p >> 5, s = (p & 31) ^ (r & 31);
    async16(xb + (size_t)sidx[r] * 256 + s * 8, &ts[(i * 256 + wv * 64) * 8]);
  }
  __syncthreads();

  // ---- Phase 1: h = relu(x @ W1 + b1), wave wv owns cols wv*64..+64 ----
  const bf16_t* w1e = w1t + (size_t)e * 65536;
  {
    f32x4 acc[4][4] = {};
#pragma unroll
    for (int kk = 0; kk < 256; kk += 64) {
#pragma unroll
      for (int kb = 0; kb < 2; ++kb) {
        const int ks = (kk >> 3) + kb * 4 + lq;   // 16B k-slot 0..31
        bf16x8 af[4], bfr[4];
#pragma unroll
        for (int mi = 0; mi < 4; ++mi) {
          int r = mi * 16 + lr;
          af[mi] = *(const bf16x8*)&ts[(r * 32 + (ks ^ (r & 31))) * 8];
        }
#pragma unroll
        for (int ni = 0; ni < 4; ++ni) {
          int n = wv * 64 + ni * 16 + lr;
          bfr[ni] = *(const bf16x8*)&w1e[(size_t)n * 256 + kk + kb * 32 + lq * 8];
        }
#pragma unroll
        for (int mi = 0; mi < 4; ++mi)
#pragma unroll
          for (int ni = 0; ni < 4; ++ni)
            acc[mi][ni] = __builtin_amdgcn_mfma_f32_16x16x32_bf16(af[mi], bfr[ni], acc[mi][ni], 0, 0, 0);
      }
    }
    float b1v[4];
#pragma unroll
    for (int ni = 0; ni < 4; ++ni) b1v[ni] = b1[e * 256 + wv * 64 + ni * 16 + lr];
    // All xs reads are done; wait for every wave before overwriting with h.
    __syncthreads();
#pragma unroll
    for (int mi = 0; mi < 4; ++mi)
#pragma unroll
      for (int ni = 0; ni < 4; ++ni)
#pragma unroll
        for (int rr = 0; rr < 4; ++rr) {
          int m = mi * 16 + lq * 4 + rr;          // C layout: row=quad*4+reg
          int n = wv * 64 + ni * 16 + lr;         //           col=lane&15
          float v = acc[mi][ni][rr] + b1v[ni];
          v = v > 0.f ? v : 0.f;
          ts[(m * 32 + ((n >> 3) ^ (m & 31))) * 8 + (n & 7)] = (bf16_t)v;
        }
  }
  __syncthreads();

  // ---- Phase 2: out = (h @ W2 + b2) * gate ----
  const bf16_t* w2e = w2t + (size_t)e * 65536;
  {
    f32x4 acc[4][4] = {};
#pragma unroll
    for (int kk = 0; kk < 256; kk += 64) {
#pragma unroll
      for (int kb = 0; kb < 2; ++kb) {
        const int ks = (kk >> 3) + kb * 4 + lq;
        bf16x8 af[4], bfr[4];
#pragma unroll
        for (int mi = 0; mi < 4; ++mi) {
          int r = mi * 16 + lr;
          af[mi] = *(const bf16x8*)&ts[(r * 32 + (ks ^ (r & 31))) * 8];
        }
#pragma unroll
        for (int ni = 0; ni < 4; ++ni) {
          int n = wv * 64 + ni * 16 + lr;
          bfr[ni] = *(const bf16x8*)&w2e[(size_t)n * 256 + kk + kb * 32 + lq * 8];
        }
#pragma unroll
        for (int mi = 0; mi < 4; ++mi)
#pragma unroll
          for (int ni = 0; ni < 4; ++ni)
            acc[mi][ni] = __builtin_amdgcn_mfma_f32_16x16x32_bf16(af[mi], bfr[ni], acc[mi][ni], 0, 0, 0);
      }
    }
    float b2v[4];
#pragma unroll
    for (int ni = 0; ni < 4; ++ni) b2v[ni] = b2[e * 256 + wv * 64 + ni * 16 + lr];
#pragma unroll
    for (int mi = 0; mi < 4; ++mi)
#pragma unroll
      for (int rr = 0; rr < 4; ++rr) {
        int m = mi * 16 + lq * 4 + rr;
        int row = tm * 64 + m;
        if (row < cnt) {
          int tok = sidx[m];
          float g = sgv[m];
#pragma unroll
          for (int ni = 0; ni < 4; ++ni) {
            int n = wv * 64 + ni * 16 + lr;
            out[(size_t)tok * 256 + n] = (acc[mi][ni][rr] + b2v[ni]) * g;
          }
        }
      }
  }
}

extern "C" void kernel_launch(void* const* d_in, const int* in_sizes, int n_in,
                              void* d_out, int out_size, void* d_ws, size_t ws_size,
                              hipStream_t stream) {
  (void)in_sizes; (void)n_in; (void)out_size; (void)ws_size;
  const float* x  = (const float*)d_in[0];
  const float* wg = (const float*)d_in[1];
  const float* W1 = (const float*)d_in[2];
  const float* b1 = (const float*)d_in[3];
  const float* W2 = (const float*)d_in[4];
  const float* b2 = (const float*)d_in[5];
  float* out = (float*)d_out;

  char* ws = (char*)d_ws;
  size_t off = 0;
  auto alloc = [&](size_t bytes) {
    void* p = ws + off;
    off += (bytes + 255) & ~(size_t)255;
    return p;
  };
  bf16_t* xb     = (bf16_t*)alloc((size_t)NTOK * DMODEL * 2);   // 32 MB
  bf16_t* w1t    = (bf16_t*)alloc((size_t)NEXP * 256 * 256 * 2);
  bf16_t* w2t    = (bf16_t*)alloc((size_t)NEXP * 256 * 256 * 2);
  int*    idxbuf = (int*)alloc((size_t)NEXP * CAP * 4);         // 2 MB
  float*  gv     = (float*)alloc((size_t)NTOK * 4);
  float*  wgT    = (float*)alloc((size_t)NEXP * DMODEL * 4);
  int*    tilel  = (int*)alloc((size_t)MAXTILES * 4);
  int*    counts = (int*)alloc((size_t)NEXP * CSTRIDE * 4);     // 256B-spread
  int*    bases  = (int*)alloc(64);
  int*    ntiles = (int*)alloc(64);

  hipLaunchKernelGGL(prep_kernel, dim3(8), dim3(256), 0, stream, wg, wgT, counts);
  hipLaunchKernelGGL(castT_kernel, dim3(8, 8, 16), dim3(32, 8), 0, stream, W1, W2, w1t, w2t);
  hipLaunchKernelGGL(gate_kernel, dim3(NTOK / 64), dim3(256), 0, stream,
                     x, wgT, xb, gv, counts, idxbuf);
  hipLaunchKernelGGL(scan_kernel, dim3(1), dim3(64), 0, stream, counts, bases, tilel, ntiles);
  hipLaunchKernelGGL(moe_gemm_kernel, dim3(MAXTILES), dim3(256), 0, stream,
                     xb, w1t, w2t, b1, b2, gv, counts, bases, idxbuf, tilel, ntiles, out);
}

// Round 4
// 201.777 us; speedup vs baseline: 1.0738x; 1.0738x over previous
//
#include <hip/hip_runtime.h>
#include <hip/hip_bf16.h>
#include <math.h>

#define NTOK 65536
#define DMODEL 256
#define NEXP 8
#define CAP 65536
#define MAXTILES 1040
#define CSTRIDE 64   // counter spacing in ints (256 B) - one L2 line per expert

typedef __bf16 bf16_t;
typedef __bf16 bf16x8 __attribute__((ext_vector_type(8)));
typedef float f32x4 __attribute__((ext_vector_type(4)));

// async global->LDS, 16B per lane. Global addr may be per-lane (gather);
// LDS dest = wave-uniform base + lane*16.
__device__ inline void async16(const void* g, void* l) {
  __builtin_amdgcn_global_load_lds(
      (const __attribute__((address_space(1))) unsigned int*)g,
      (__attribute__((address_space(3))) unsigned int*)l, 16, 0, 0);
}

// Prep: zero spread counters + transpose gate weights fp32 [E][D] -> [D][E].
__global__ void prep_kernel(const float* __restrict__ wg, float* __restrict__ wgT,
                            int* __restrict__ counts) {
  int t = blockIdx.x * 256 + threadIdx.x;
  if (t < NEXP * DMODEL) wgT[t] = wg[(t & 7) * 256 + (t >> 3)];
  if (t < NEXP * CSTRIDE) counts[t] = 0;
}

// Cast W1/W2 fp32 [e][k][n] -> bf16 transposed [e][n][k] via 32x32 LDS tile.
__global__ __launch_bounds__(256) void castT_kernel(
    const float* __restrict__ W1, const float* __restrict__ W2,
    bf16_t* __restrict__ w1t, bf16_t* __restrict__ w2t) {
  __shared__ float tile[32][33];
  const int m = blockIdx.z;
  const float* src = (m < 8) ? (W1 + (size_t)m * 65536) : (W2 + (size_t)(m - 8) * 65536);
  bf16_t* dst = (m < 8) ? (w1t + (size_t)m * 65536) : (w2t + (size_t)(m - 8) * 65536);
  const int x0 = blockIdx.x * 32, y0 = blockIdx.y * 32;
  const int tx = threadIdx.x, ty = threadIdx.y;
#pragma unroll
  for (int i = 0; i < 4; ++i)
    tile[ty + i * 8][tx] = src[(size_t)(y0 + ty + i * 8) * 256 + x0 + tx];
  __syncthreads();
#pragma unroll
  for (int i = 0; i < 4; ++i)
    dst[(size_t)(x0 + ty + i * 8) * 256 + y0 + tx] = (bf16_t)tile[tx][ty + i * 8];
}

// Gate v7 (unchanged from validated round-1 version; latency-bound at ~43us,
// to be attacked separately).
__global__ __launch_bounds__(256) void gate_kernel(
    const float* __restrict__ x, const float* __restrict__ wgT,
    bf16_t* __restrict__ xb, float* __restrict__ gateval,
    int* __restrict__ counts, int* __restrict__ idxbuf) {
  __shared__ __align__(16) float xs[64 * 256];   // 64 KB, xor-swizzled rows
  __shared__ double part[3][64][9];              // +1 pad: 18-word stride, 2-way (free)
  const int th = threadIdx.x;
  const int lane = th & 63;
  const int wv = th >> 6;                        // wave id = segment 0..3
  const int tokbase = blockIdx.x * 64;

  // Stage: 4096 16B slots; physical slot p = i*256+th holds logical
  // (r = p>>6, c = (p&63) ^ (r&31)). Source is per-lane, dest linear.
#pragma unroll
  for (int i = 0; i < 16; ++i) {
    int p = i * 256 + th;
    int r = p >> 6;
    int c = (p & 63) ^ (r & 31);
    async16(x + (size_t)(tokbase + r) * 256 + c * 4,
            &xs[(i * 256 + wv * 64) * 4]);
  }
  __syncthreads();  // drains vmcnt (compiler emits waitcnt before s_barrier)

  // Cast pass: issue the 32 MB of bf16 stores early so they drain
  // under the compute below. Output tile is contiguous: 2048 16B slots.
#pragma unroll
  for (int i = 0; i < 8; ++i) {
    int p = i * 256 + th;                 // bf16 16B slot: r = p>>5, cb = p&31
    int r = p >> 5, cb = p & 31;
    int mk = r & 31;
    f32x4 a = *(const f32x4*)&xs[r * 256 + (((2 * cb) ^ mk) * 4)];
    f32x4 b = *(const f32x4*)&xs[r * 256 + (((2 * cb + 1) ^ mk) * 4)];
    bf16x8 bv;
    bv[0] = (bf16_t)a[0]; bv[1] = (bf16_t)a[1];
    bv[2] = (bf16_t)a[2]; bv[3] = (bf16_t)a[3];
    bv[4] = (bf16_t)b[0]; bv[5] = (bf16_t)b[1];
    bv[6] = (bf16_t)b[2]; bv[7] = (bf16_t)b[3];
    *(bf16x8*)(xb + (size_t)tokbase * 256 + (size_t)p * 8) = bv;
  }

  // Partial dots: thread (tok=lane, seg=wv) covers dims [seg*64, seg*64+64).
  const float* wp = wgT + wv * 64 * 8;    // [64 dims][8 experts], wave-uniform
  const int xm = lane & 31;
  double acc[8] = {0, 0, 0, 0, 0, 0, 0, 0};
#pragma unroll
  for (int u = 0; u < 8; ++u) {           // 8-dim chain u (dims seg*64+u*8..+7)
    int c0 = 16 * wv + 2 * u;
    f32x4 a = *(const f32x4*)&xs[lane * 256 + ((c0 ^ xm) * 4)];
    f32x4 b = *(const f32x4*)&xs[lane * 256 + (((c0 + 1) ^ xm) * 4)];
    float xv[8] = {a[0], a[1], a[2], a[3], b[0], b[1], b[2], b[3]};
    float s[8] = {0.f, 0.f, 0.f, 0.f, 0.f, 0.f, 0.f, 0.f};
#pragma unroll
    for (int j = 0; j < 8; ++j) {         // vectorized weights: 2x16B per dim
      f32x4 w0 = *(const f32x4*)&wp[(u * 8 + j) * 8];
      f32x4 w1 = *(const f32x4*)&wp[(u * 8 + j) * 8 + 4];
      s[0] = fmaf(xv[j], w0[0], s[0]); s[1] = fmaf(xv[j], w0[1], s[1]);
      s[2] = fmaf(xv[j], w0[2], s[2]); s[3] = fmaf(xv[j], w0[3], s[3]);
      s[4] = fmaf(xv[j], w1[0], s[4]); s[5] = fmaf(xv[j], w1[1], s[5]);
      s[6] = fmaf(xv[j], w1[2], s[6]); s[7] = fmaf(xv[j], w1[3], s[7]);
    }
#pragma unroll
    for (int e = 0; e < 8; ++e) acc[e] += (double)s[e];
  }

  if (wv > 0) {
#pragma unroll
    for (int e = 0; e < 8; ++e) part[wv - 1][lane][e] = acc[e];
  }
  __syncthreads();
  if (wv == 0) {
#pragma unroll
    for (int s2 = 0; s2 < 3; ++s2)
#pragma unroll
      for (int e = 0; e < 8; ++e) acc[e] += part[s2][lane][e];
    double m = acc[0]; int bi = 0;
#pragma unroll
    for (int e = 1; e < 8; ++e) if (acc[e] > m) { m = acc[e]; bi = e; }
    float denom = 0.f;
#pragma unroll
    for (int e = 0; e < 8; ++e) denom += __expf((float)(acc[e] - m));
    const int tok = tokbase + lane;
    gateval[tok] = 1.0f / denom;
    unsigned long long mymask = 0;
#pragma unroll
    for (int e = 0; e < NEXP; ++e) {
      unsigned long long mk = __ballot(bi == e);
      if (lane == e) mymask = mk;
    }
    int mybase = 0;
    if (lane < NEXP) mybase = atomicAdd(&counts[lane * CSTRIDE], (int)__popcll(mymask));
#pragma unroll
    for (int e = 0; e < NEXP; ++e) {
      unsigned long long mk = __ballot(bi == e);
      int b = __shfl(mybase, e, 64);
      if (bi == e) {
        int pos = b + (int)__popcll(mk & ((1ull << lane) - 1ull));
        idxbuf[e * CAP + pos] = tok;
      }
    }
  }
}

// Scan: token bases + device-side tile list (e in bits 0..2, tm in bits 3+).
// Tiles are 64 rows.
__global__ void scan_kernel(const int* __restrict__ counts, int* __restrict__ bases,
                            int* __restrict__ tl, int* __restrict__ ntiles) {
  int t = threadIdx.x;
  if (t == 0) {
    int s = 0, n = 0;
    for (int e = 0; e < NEXP; ++e) {
      bases[e] = s; s += counts[e * CSTRIDE];
      n += (counts[e * CSTRIDE] + 63) >> 6;
    }
    *ntiles = n;
  }
  if (t < NEXP) {
    int off = 0;
    for (int j = 0; j < t; ++j) off += (counts[j * CSTRIDE] + 63) >> 6;
    int n = (counts[t * CSTRIDE] + 63) >> 6;
    for (int k = 0; k < n; ++k) tl[off + k] = t | (k << 3);
  }
}

// Fused MoE GEMM v3: v2's LDS overlay (33 KB -> 4 blocks/CU by LDS) but with
// PLAIN __launch_bounds__(256): round-3's (256,4) coerced VGPR 108->64 and
// spilled acc to scratch (+52 MB WRITE / +26 MB FETCH per dispatch, dur
// 68->75). At the natural ~108 VGPR the HW already allows 4 waves/SIMD
// (occupancy steps at 64/128/256), so the LDS overlay alone delivers
// 4 blocks/CU without spills.
__global__ __launch_bounds__(256) void moe_gemm_kernel(
    const bf16_t* __restrict__ xb, const bf16_t* __restrict__ w1t,
    const bf16_t* __restrict__ w2t, const float* __restrict__ b1,
    const float* __restrict__ b2, const float* __restrict__ gateval,
    const int* __restrict__ counts, const int* __restrict__ bases,
    const int* __restrict__ idxbuf, const int* __restrict__ tl,
    const int* __restrict__ ntiles, float* __restrict__ out) {
  if ((int)blockIdx.x >= *ntiles) return;
  const int tle = tl[blockIdx.x];
  const int e = tle & 7, tm = tle >> 3;
  const int cnt = counts[e * CSTRIDE];
  (void)bases;
  __shared__ __align__(16) bf16_t ts[64 * 256];   // 32 KB: x tile, then h tile
  __shared__ int sidx[64];
  __shared__ float sgv[64];
  const int th = threadIdx.x;
  const int lane = th & 63, wv = th >> 6;
  const int lr = lane & 15, lq = lane >> 4;
  if (th < 64) {
    int r = tm * 64 + th;
    int t = idxbuf[e * CAP + (r < cnt ? r : cnt - 1)];
    sidx[th] = t;
    sgv[th] = gateval[t];
  }
  __syncthreads();
  // Stage x tile: 2048 16B slots; physical slot p holds logical k-slot
  // (p&31)^(r&31) of row r = p>>5. Source per-lane, dest linear.
#pragma unroll
  for (int i = 0; i < 8; ++i) {
    int p = i * 256 + th;
    int r = p >> 5, s = (p & 31) ^ (r & 31);
    async16(xb + (size_t)sidx[r] * 256 + s * 8, &ts[(i * 256 + wv * 64) * 8]);
  }
  __syncthreads();

  // ---- Phase 1: h = relu(x @ W1 + b1), wave wv owns cols wv*64..+64 ----
  const bf16_t* w1e = w1t + (size_t)e * 65536;
  {
    f32x4 acc[4][4] = {};
#pragma unroll
    for (int kk = 0; kk < 256; kk += 64) {
#pragma unroll
      for (int kb = 0; kb < 2; ++kb) {
        const int ks = (kk >> 3) + kb * 4 + lq;   // 16B k-slot 0..31
        bf16x8 af[4], bfr[4];
#pragma unroll
        for (int mi = 0; mi < 4; ++mi) {
          int r = mi * 16 + lr;
          af[mi] = *(const bf16x8*)&ts[(r * 32 + (ks ^ (r & 31))) * 8];
        }
#pragma unroll
        for (int ni = 0; ni < 4; ++ni) {
          int n = wv * 64 + ni * 16 + lr;
          bfr[ni] = *(const bf16x8*)&w1e[(size_t)n * 256 + kk + kb * 32 + lq * 8];
        }
#pragma unroll
        for (int mi = 0; mi < 4; ++mi)
#pragma unroll
          for (int ni = 0; ni < 4; ++ni)
            acc[mi][ni] = __builtin_amdgcn_mfma_f32_16x16x32_bf16(af[mi], bfr[ni], acc[mi][ni], 0, 0, 0);
      }
    }
    float b1v[4];
#pragma unroll
    for (int ni = 0; ni < 4; ++ni) b1v[ni] = b1[e * 256 + wv * 64 + ni * 16 + lr];
    // All xs reads are done; wait for every wave before overwriting with h.
    __syncthreads();
#pragma unroll
    for (int mi = 0; mi < 4; ++mi)
#pragma unroll
      for (int ni = 0; ni < 4; ++ni)
#pragma unroll
        for (int rr = 0; rr < 4; ++rr) {
          int m = mi * 16 + lq * 4 + rr;          // C layout: row=quad*4+reg
          int n = wv * 64 + ni * 16 + lr;         //           col=lane&15
          float v = acc[mi][ni][rr] + b1v[ni];
          v = v > 0.f ? v : 0.f;
          ts[(m * 32 + ((n >> 3) ^ (m & 31))) * 8 + (n & 7)] = (bf16_t)v;
        }
  }
  __syncthreads();

  // ---- Phase 2: out = (h @ W2 + b2) * gate ----
  const bf16_t* w2e = w2t + (size_t)e * 65536;
  {
    f32x4 acc[4][4] = {};
#pragma unroll
    for (int kk = 0; kk < 256; kk += 64) {
#pragma unroll
      for (int kb = 0; kb < 2; ++kb) {
        const int ks = (kk >> 3) + kb * 4 + lq;
        bf16x8 af[4], bfr[4];
#pragma unroll
        for (int mi = 0; mi < 4; ++mi) {
          int r = mi * 16 + lr;
          af[mi] = *(const bf16x8*)&ts[(r * 32 + (ks ^ (r & 31))) * 8];
        }
#pragma unroll
        for (int ni = 0; ni < 4; ++ni) {
          int n = wv * 64 + ni * 16 + lr;
          bfr[ni] = *(const bf16x8*)&w2e[(size_t)n * 256 + kk + kb * 32 + lq * 8];
        }
#pragma unroll
        for (int mi = 0; mi < 4; ++mi)
#pragma unroll
          for (int ni = 0; ni < 4; ++ni)
            acc[mi][ni] = __builtin_amdgcn_mfma_f32_16x16x32_bf16(af[mi], bfr[ni], acc[mi][ni], 0, 0, 0);
      }
    }
    float b2v[4];
#pragma unroll
    for (int ni = 0; ni < 4; ++ni) b2v[ni] = b2[e * 256 + wv * 64 + ni * 16 + lr];
#pragma unroll
    for (int mi = 0; mi < 4; ++mi)
#pragma unroll
      for (int rr = 0; rr < 4; ++rr) {
        int m = mi * 16 + lq * 4 + rr;
        int row = tm * 64 + m;
        if (row < cnt) {
          int tok = sidx[m];
          float g = sgv[m];
#pragma unroll
          for (int ni = 0; ni < 4; ++ni) {
            int n = wv * 64 + ni * 16 + lr;
            out[(size_t)tok * 256 + n] = (acc[mi][ni][rr] + b2v[ni]) * g;
          }
        }
      }
  }
}

extern "C" void kernel_launch(void* const* d_in, const int* in_sizes, int n_in,
                              void* d_out, int out_size, void* d_ws, size_t ws_size,
                              hipStream_t stream) {
  (void)in_sizes; (void)n_in; (void)out_size; (void)ws_size;
  const float* x  = (const float*)d_in[0];
  const float* wg = (const float*)d_in[1];
  const float* W1 = (const float*)d_in[2];
  const float* b1 = (const float*)d_in[3];
  const float* W2 = (const float*)d_in[4];
  const float* b2 = (const float*)d_in[5];
  float* out = (float*)d_out;

  char* ws = (char*)d_ws;
  size_t off = 0;
  auto alloc = [&](size_t bytes) {
    void* p = ws + off;
    off += (bytes + 255) & ~(size_t)255;
    return p;
  };
  bf16_t* xb     = (bf16_t*)alloc((size_t)NTOK * DMODEL * 2);   // 32 MB
  bf16_t* w1t    = (bf16_t*)alloc((size_t)NEXP * 256 * 256 * 2);
  bf16_t* w2t    = (bf16_t*)alloc((size_t)NEXP * 256 * 256 * 2);
  int*    idxbuf = (int*)alloc((size_t)NEXP * CAP * 4);         // 2 MB
  float*  gv     = (float*)alloc((size_t)NTOK * 4);
  float*  wgT    = (float*)alloc((size_t)NEXP * DMODEL * 4);
  int*    tilel  = (int*)alloc((size_t)MAXTILES * 4);
  int*    counts = (int*)alloc((size_t)NEXP * CSTRIDE * 4);     // 256B-spread
  int*    bases  = (int*)alloc(64);
  int*    ntiles = (int*)alloc(64);

  hipLaunchKernelGGL(prep_kernel, dim3(8), dim3(256), 0, stream, wg, wgT, counts);
  hipLaunchKernelGGL(castT_kernel, dim3(8, 8, 16), dim3(32, 8), 0, stream, W1, W2, w1t, w2t);
  hipLaunchKernelGGL(gate_kernel, dim3(NTOK / 64), dim3(256), 0, stream,
                     x, wgT, xb, gv, counts, idxbuf);
  hipLaunchKernelGGL(scan_kernel, dim3(1), dim3(64), 0, stream, counts, bases, tilel, ntiles);
  hipLaunchKernelGGL(moe_gemm_kernel, dim3(MAXTILES), dim3(256), 0, stream,
                     xb, w1t, w2t, b1, b2, gv, counts, bases, idxbuf, tilel, ntiles, out);
}

// Round 5
// 200.026 us; speedup vs baseline: 1.0832x; 1.0088x over previous
//
#include <hip/hip_runtime.h>
#include <hip/hip_bf16.h>
#include <math.h>

#define NTOK 65536
#define DMODEL 256
#define NEXP 8
#define CAP 65536
#define MAXTILES 1040
#define CSTRIDE 64   // counter spacing in ints (256 B) - one L2 line per expert

typedef __bf16 bf16_t;
typedef __bf16 bf16x8 __attribute__((ext_vector_type(8)));
typedef float f32x4 __attribute__((ext_vector_type(4)));

// async global->LDS, 16B per lane. Global addr may be per-lane (gather);
// LDS dest = wave-uniform base + lane*16.
__device__ inline void async16(const void* g, void* l) {
  __builtin_amdgcn_global_load_lds(
      (const __attribute__((address_space(1))) unsigned int*)g,
      (__attribute__((address_space(3))) unsigned int*)l, 16, 0, 0);
}

// Prep: zero spread counters + transpose gate weights fp32 [E][D] -> [D][E].
__global__ void prep_kernel(const float* __restrict__ wg, float* __restrict__ wgT,
                            int* __restrict__ counts) {
  int t = blockIdx.x * 256 + threadIdx.x;
  if (t < NEXP * DMODEL) wgT[t] = wg[(t & 7) * 256 + (t >> 3)];
  if (t < NEXP * CSTRIDE) counts[t] = 0;
}

// Cast W1/W2 fp32 [e][k][n] -> bf16 transposed [e][n][k] via 32x32 LDS tile.
__global__ __launch_bounds__(256) void castT_kernel(
    const float* __restrict__ W1, const float* __restrict__ W2,
    bf16_t* __restrict__ w1t, bf16_t* __restrict__ w2t) {
  __shared__ float tile[32][33];
  const int m = blockIdx.z;
  const float* src = (m < 8) ? (W1 + (size_t)m * 65536) : (W2 + (size_t)(m - 8) * 65536);
  bf16_t* dst = (m < 8) ? (w1t + (size_t)m * 65536) : (w2t + (size_t)(m - 8) * 65536);
  const int x0 = blockIdx.x * 32, y0 = blockIdx.y * 32;
  const int tx = threadIdx.x, ty = threadIdx.y;
#pragma unroll
  for (int i = 0; i < 4; ++i)
    tile[ty + i * 8][tx] = src[(size_t)(y0 + ty + i * 8) * 256 + x0 + tx];
  __syncthreads();
#pragma unroll
  for (int i = 0; i < 4; ++i)
    dst[(size_t)(x0 + ty + i * 8) * 256 + y0 + tx] = (bf16_t)tile[tx][ty + i * 8];
}

// Gate v7 (unchanged from validated round-1 version; latency-bound at ~43us,
// to be attacked separately).
__global__ __launch_bounds__(256) void gate_kernel(
    const float* __restrict__ x, const float* __restrict__ wgT,
    bf16_t* __restrict__ xb, float* __restrict__ gateval,
    int* __restrict__ counts, int* __restrict__ idxbuf) {
  __shared__ __align__(16) float xs[64 * 256];   // 64 KB, xor-swizzled rows
  __shared__ double part[3][64][9];              // +1 pad: 18-word stride, 2-way (free)
  const int th = threadIdx.x;
  const int lane = th & 63;
  const int wv = th >> 6;                        // wave id = segment 0..3
  const int tokbase = blockIdx.x * 64;

  // Stage: 4096 16B slots; physical slot p = i*256+th holds logical
  // (r = p>>6, c = (p&63) ^ (r&31)). Source is per-lane, dest linear.
#pragma unroll
  for (int i = 0; i < 16; ++i) {
    int p = i * 256 + th;
    int r = p >> 6;
    int c = (p & 63) ^ (r & 31);
    async16(x + (size_t)(tokbase + r) * 256 + c * 4,
            &xs[(i * 256 + wv * 64) * 4]);
  }
  __syncthreads();  // drains vmcnt (compiler emits waitcnt before s_barrier)

  // Cast pass: issue the 32 MB of bf16 stores early so they drain
  // under the compute below. Output tile is contiguous: 2048 16B slots.
#pragma unroll
  for (int i = 0; i < 8; ++i) {
    int p = i * 256 + th;                 // bf16 16B slot: r = p>>5, cb = p&31
    int r = p >> 5, cb = p & 31;
    int mk = r & 31;
    f32x4 a = *(const f32x4*)&xs[r * 256 + (((2 * cb) ^ mk) * 4)];
    f32x4 b = *(const f32x4*)&xs[r * 256 + (((2 * cb + 1) ^ mk) * 4)];
    bf16x8 bv;
    bv[0] = (bf16_t)a[0]; bv[1] = (bf16_t)a[1];
    bv[2] = (bf16_t)a[2]; bv[3] = (bf16_t)a[3];
    bv[4] = (bf16_t)b[0]; bv[5] = (bf16_t)b[1];
    bv[6] = (bf16_t)b[2]; bv[7] = (bf16_t)b[3];
    *(bf16x8*)(xb + (size_t)tokbase * 256 + (size_t)p * 8) = bv;
  }

  // Partial dots: thread (tok=lane, seg=wv) covers dims [seg*64, seg*64+64).
  const float* wp = wgT + wv * 64 * 8;    // [64 dims][8 experts], wave-uniform
  const int xm = lane & 31;
  double acc[8] = {0, 0, 0, 0, 0, 0, 0, 0};
#pragma unroll
  for (int u = 0; u < 8; ++u) {           // 8-dim chain u (dims seg*64+u*8..+7)
    int c0 = 16 * wv + 2 * u;
    f32x4 a = *(const f32x4*)&xs[lane * 256 + ((c0 ^ xm) * 4)];
    f32x4 b = *(const f32x4*)&xs[lane * 256 + (((c0 + 1) ^ xm) * 4)];
    float xv[8] = {a[0], a[1], a[2], a[3], b[0], b[1], b[2], b[3]};
    float s[8] = {0.f, 0.f, 0.f, 0.f, 0.f, 0.f, 0.f, 0.f};
#pragma unroll
    for (int j = 0; j < 8; ++j) {         // vectorized weights: 2x16B per dim
      f32x4 w0 = *(const f32x4*)&wp[(u * 8 + j) * 8];
      f32x4 w1 = *(const f32x4*)&wp[(u * 8 + j) * 8 + 4];
      s[0] = fmaf(xv[j], w0[0], s[0]); s[1] = fmaf(xv[j], w0[1], s[1]);
      s[2] = fmaf(xv[j], w0[2], s[2]); s[3] = fmaf(xv[j], w0[3], s[3]);
      s[4] = fmaf(xv[j], w1[0], s[4]); s[5] = fmaf(xv[j], w1[1], s[5]);
      s[6] = fmaf(xv[j], w1[2], s[6]); s[7] = fmaf(xv[j], w1[3], s[7]);
    }
#pragma unroll
    for (int e = 0; e < 8; ++e) acc[e] += (double)s[e];
  }

  if (wv > 0) {
#pragma unroll
    for (int e = 0; e < 8; ++e) part[wv - 1][lane][e] = acc[e];
  }
  __syncthreads();
  if (wv == 0) {
#pragma unroll
    for (int s2 = 0; s2 < 3; ++s2)
#pragma unroll
      for (int e = 0; e < 8; ++e) acc[e] += part[s2][lane][e];
    double m = acc[0]; int bi = 0;
#pragma unroll
    for (int e = 1; e < 8; ++e) if (acc[e] > m) { m = acc[e]; bi = e; }
    float denom = 0.f;
#pragma unroll
    for (int e = 0; e < 8; ++e) denom += __expf((float)(acc[e] - m));
    const int tok = tokbase + lane;
    gateval[tok] = 1.0f / denom;
    unsigned long long mymask = 0;
#pragma unroll
    for (int e = 0; e < NEXP; ++e) {
      unsigned long long mk = __ballot(bi == e);
      if (lane == e) mymask = mk;
    }
    int mybase = 0;
    if (lane < NEXP) mybase = atomicAdd(&counts[lane * CSTRIDE], (int)__popcll(mymask));
#pragma unroll
    for (int e = 0; e < NEXP; ++e) {
      unsigned long long mk = __ballot(bi == e);
      int b = __shfl(mybase, e, 64);
      if (bi == e) {
        int pos = b + (int)__popcll(mk & ((1ull << lane) - 1ull));
        idxbuf[e * CAP + pos] = tok;
      }
    }
  }
}

// Scan: token bases + device-side tile list (e in bits 0..2, tm in bits 3+).
// Tiles are 64 rows.
__global__ void scan_kernel(const int* __restrict__ counts, int* __restrict__ bases,
                            int* __restrict__ tl, int* __restrict__ ntiles) {
  int t = threadIdx.x;
  if (t == 0) {
    int s = 0, n = 0;
    for (int e = 0; e < NEXP; ++e) {
      bases[e] = s; s += counts[e * CSTRIDE];
      n += (counts[e * CSTRIDE] + 63) >> 6;
    }
    *ntiles = n;
  }
  if (t < NEXP) {
    int off = 0;
    for (int j = 0; j < t; ++j) off += (counts[j * CSTRIDE] + 63) >> 6;
    int n = (counts[t * CSTRIDE] + 63) >> 6;
    for (int k = 0; k < n; ++k) tl[off + k] = t | (k << 3);
  }
}

// Fused MoE GEMM v4: register-budget restructure. Rounds 2/4 both sat at 16%
// occupancy (2 blocks/CU) independent of LDS because the UNIFIED gfx950 reg
// file counts AGPRs: 108 arch + 64 acc ~= 172 total -> 2 waves/SIMD. Round 3
// proved 128-total doubles occupancy (31%) but spilled at acc[4][4].
// v4 halves the per-wave accumulator instead: 512 thr / 8 waves, each wave
// owns a 64x32 strip (acc[4][2]=32 regs + af[4]+bfr[2]=24), so 128 total fits
// WITHOUT spills. __launch_bounds__(512,4) pins 4 waves/SIMD. Block still
// computes the full 64x256 h tile (phase 2 needs all h columns). Numerics,
// swizzle, and MFMA order per output element are unchanged (bit-identical).
__global__ __launch_bounds__(512, 4) void moe_gemm_kernel(
    const bf16_t* __restrict__ xb, const bf16_t* __restrict__ w1t,
    const bf16_t* __restrict__ w2t, const float* __restrict__ b1,
    const float* __restrict__ b2, const float* __restrict__ gateval,
    const int* __restrict__ counts, const int* __restrict__ bases,
    const int* __restrict__ idxbuf, const int* __restrict__ tl,
    const int* __restrict__ ntiles, float* __restrict__ out) {
  if ((int)blockIdx.x >= *ntiles) return;
  const int tle = tl[blockIdx.x];
  const int e = tle & 7, tm = tle >> 3;
  const int cnt = counts[e * CSTRIDE];
  (void)bases;
  __shared__ __align__(16) bf16_t ts[64 * 256];   // 32 KB: x tile, then h tile
  __shared__ int sidx[64];
  __shared__ float sgv[64];
  const int th = threadIdx.x;
  const int lane = th & 63, wv = th >> 6;         // wv 0..7
  const int lr = lane & 15, lq = lane >> 4;
  if (th < 64) {
    int r = tm * 64 + th;
    int t = idxbuf[e * CAP + (r < cnt ? r : cnt - 1)];
    sidx[th] = t;
    sgv[th] = gateval[t];
  }
  __syncthreads();
  // Stage x tile: 2048 16B slots over 512 threads; physical slot p holds
  // logical k-slot (p&31)^(r&31) of row r = p>>5. Source per-lane, dest linear.
#pragma unroll
  for (int i = 0; i < 4; ++i) {
    int p = i * 512 + th;
    int r = p >> 5, s = (p & 31) ^ (r & 31);
    async16(xb + (size_t)sidx[r] * 256 + s * 8, &ts[(i * 512 + wv * 64) * 8]);
  }
  __syncthreads();

  // ---- Phase 1: h = relu(x @ W1 + b1), wave wv owns cols wv*32..+32 ----
  const bf16_t* w1e = w1t + (size_t)e * 65536;
  {
    f32x4 acc[4][2] = {};
#pragma unroll
    for (int kk = 0; kk < 256; kk += 64) {
#pragma unroll
      for (int kb = 0; kb < 2; ++kb) {
        const int ks = (kk >> 3) + kb * 4 + lq;   // 16B k-slot 0..31
        bf16x8 af[4], bfr[2];
#pragma unroll
        for (int mi = 0; mi < 4; ++mi) {
          int r = mi * 16 + lr;
          af[mi] = *(const bf16x8*)&ts[(r * 32 + (ks ^ (r & 31))) * 8];
        }
#pragma unroll
        for (int ni = 0; ni < 2; ++ni) {
          int n = wv * 32 + ni * 16 + lr;
          bfr[ni] = *(const bf16x8*)&w1e[(size_t)n * 256 + kk + kb * 32 + lq * 8];
        }
#pragma unroll
        for (int mi = 0; mi < 4; ++mi)
#pragma unroll
          for (int ni = 0; ni < 2; ++ni)
            acc[mi][ni] = __builtin_amdgcn_mfma_f32_16x16x32_bf16(af[mi], bfr[ni], acc[mi][ni], 0, 0, 0);
      }
    }
    float b1v[2];
#pragma unroll
    for (int ni = 0; ni < 2; ++ni) b1v[ni] = b1[e * 256 + wv * 32 + ni * 16 + lr];
    // All x-tile reads are done; wait for every wave before overwriting with h.
    __syncthreads();
#pragma unroll
    for (int mi = 0; mi < 4; ++mi)
#pragma unroll
      for (int ni = 0; ni < 2; ++ni)
#pragma unroll
        for (int rr = 0; rr < 4; ++rr) {
          int m = mi * 16 + lq * 4 + rr;          // C layout: row=quad*4+reg
          int n = wv * 32 + ni * 16 + lr;         //           col=lane&15
          float v = acc[mi][ni][rr] + b1v[ni];
          v = v > 0.f ? v : 0.f;
          ts[(m * 32 + ((n >> 3) ^ (m & 31))) * 8 + (n & 7)] = (bf16_t)v;
        }
  }
  __syncthreads();

  // ---- Phase 2: out = (h @ W2 + b2) * gate ----
  const bf16_t* w2e = w2t + (size_t)e * 65536;
  {
    f32x4 acc[4][2] = {};
#pragma unroll
    for (int kk = 0; kk < 256; kk += 64) {
#pragma unroll
      for (int kb = 0; kb < 2; ++kb) {
        const int ks = (kk >> 3) + kb * 4 + lq;
        bf16x8 af[4], bfr[2];
#pragma unroll
        for (int mi = 0; mi < 4; ++mi) {
          int r = mi * 16 + lr;
          af[mi] = *(const bf16x8*)&ts[(r * 32 + (ks ^ (r & 31))) * 8];
        }
#pragma unroll
        for (int ni = 0; ni < 2; ++ni) {
          int n = wv * 32 + ni * 16 + lr;
          bfr[ni] = *(const bf16x8*)&w2e[(size_t)n * 256 + kk + kb * 32 + lq * 8];
        }
#pragma unroll
        for (int mi = 0; mi < 4; ++mi)
#pragma unroll
          for (int ni = 0; ni < 2; ++ni)
            acc[mi][ni] = __builtin_amdgcn_mfma_f32_16x16x32_bf16(af[mi], bfr[ni], acc[mi][ni], 0, 0, 0);
      }
    }
    float b2v[2];
#pragma unroll
    for (int ni = 0; ni < 2; ++ni) b2v[ni] = b2[e * 256 + wv * 32 + ni * 16 + lr];
#pragma unroll
    for (int mi = 0; mi < 4; ++mi)
#pragma unroll
      for (int rr = 0; rr < 4; ++rr) {
        int m = mi * 16 + lq * 4 + rr;
        int row = tm * 64 + m;
        if (row < cnt) {
          int tok = sidx[m];
          float g = sgv[m];
#pragma unroll
          for (int ni = 0; ni < 2; ++ni) {
            int n = wv * 32 + ni * 16 + lr;
            out[(size_t)tok * 256 + n] = (acc[mi][ni][rr] + b2v[ni]) * g;
          }
        }
      }
  }
}

extern "C" void kernel_launch(void* const* d_in, const int* in_sizes, int n_in,
                              void* d_out, int out_size, void* d_ws, size_t ws_size,
                              hipStream_t stream) {
  (void)in_sizes; (void)n_in; (void)out_size; (void)ws_size;
  const float* x  = (const float*)d_in[0];
  const float* wg = (const float*)d_in[1];
  const float* W1 = (const float*)d_in[2];
  const float* b1 = (const float*)d_in[3];
  const float* W2 = (const float*)d_in[4];
  const float* b2 = (const float*)d_in[5];
  float* out = (float*)d_out;

  char* ws = (char*)d_ws;
  size_t off = 0;
  auto alloc = [&](size_t bytes) {
    void* p = ws + off;
    off += (bytes + 255) & ~(size_t)255;
    return p;
  };
  bf16_t* xb     = (bf16_t*)alloc((size_t)NTOK * DMODEL * 2);   // 32 MB
  bf16_t* w1t    = (bf16_t*)alloc((size_t)NEXP * 256 * 256 * 2);
  bf16_t* w2t    = (bf16_t*)alloc((size_t)NEXP * 256 * 256 * 2);
  int*    idxbuf = (int*)alloc((size_t)NEXP * CAP * 4);         // 2 MB
  float*  gv     = (float*)alloc((size_t)NTOK * 4);
  float*  wgT    = (float*)alloc((size_t)NEXP * DMODEL * 4);
  int*    tilel  = (int*)alloc((size_t)MAXTILES * 4);
  int*    counts = (int*)alloc((size_t)NEXP * CSTRIDE * 4);     // 256B-spread
  int*    bases  = (int*)alloc(64);
  int*    ntiles = (int*)alloc(64);

  hipLaunchKernelGGL(prep_kernel, dim3(8), dim3(256), 0, stream, wg, wgT, counts);
  hipLaunchKernelGGL(castT_kernel, dim3(8, 8, 16), dim3(32, 8), 0, stream, W1, W2, w1t, w2t);
  hipLaunchKernelGGL(gate_kernel, dim3(NTOK / 64), dim3(256), 0, stream,
                     x, wgT, xb, gv, counts, idxbuf);
  hipLaunchKernelGGL(scan_kernel, dim3(1), dim3(64), 0, stream, counts, bases, tilel, ntiles);
  hipLaunchKernelGGL(moe_gemm_kernel, dim3(MAXTILES), dim3(512), 0, stream,
                     xb, w1t, w2t, b1, b2, gv, counts, bases, idxbuf, tilel, ntiles, out);
}